// Round 4
// baseline (226.243 us; speedup 1.0000x reference)
//
#include <hip/hip_runtime.h>

// KDE joint histogram, quadrant-compacted split-K INT8 MFMA GEMM (R15).
// joint[b,i,j] = sum_k kx[b,k,i]*ky[b,k,j]; q = round(127*exp(-0.5 d^2))
// (i8 support ±3.33 bins -> 7-bin window; 127^2 scale cancels in norm;
// i32 accumulation exact).
// R15: each particle's window touches 1 (or 2, straddle) of the 2x2 128-bin
// quadrants per axis -> bucket pass compacts per-(b,ti,tj) lists with
// PRECOMPUTED quantized windows (16B/entry: rxl,ryl,qx[7],qy[7]).
// Gemm K-depth per quadrant block drops 50000 -> ~13100: KSTEPS 17 -> ~5,
// and the in-loop scatter loses all exp2 VALU. Accumulated integers are
// bit-identical to the dense version (clipped cells -> dump row, never read).
// Lessons: R12 wider tile REGRESSED; R13 read-hoist+setprio REGRESSED;
// R14 balanced waves +2.1us. Clean/write same-column ordering is safe only
// because the h-split lane pair lives in ONE wave (cleans precede writes in
// wave program order) — do NOT move h across waves.

#define B_     4
#define N_     50000
#define M_     256
#define BK     64
#define NCH    48               // grid 4*48*4 = 768 = 3 blocks/CU (LDS 41.3KB)
#define LDKB   80               // tile row stride BYTES (16B-aligned)
#define ROWS   129              // 128 + dump row for clipped writes
#define AXB    (ROWS * LDKB)    // bytes per axis tile (10320)
#define BUFB   (2 * AXB)        // bytes per ping-pong buffer (20640)
#define BLOCK  256
#define CAP    65536            // entries per list (>= max possible N_)
#define CS2    0.72134752f      // 0.5*log2(e)
#define L127   6.9886847f       // log2(127)

#if __has_builtin(__builtin_amdgcn_exp2f)
  #define EXP2(t) __builtin_amdgcn_exp2f(t)
#else
  #define EXP2(t) exp2f(t)
#endif

typedef __attribute__((ext_vector_type(4))) int i32x4;

__device__ __forceinline__ unsigned short bf16ru(float f) {  // round-half-up
    return (unsigned short)((__builtin_bit_cast(unsigned, f) + 0x8000u) >> 16);
}
__device__ __forceinline__ float bf2f(unsigned short u) {
    return __builtin_bit_cast(float, ((unsigned)u) << 16);
}

// ---- pass 0: bucket particles into quadrant lists, precompute windows ----
__global__ __launch_bounds__(BLOCK) void kde_bucket(
    const float* __restrict__ xs, const float* __restrict__ ys,
    const float* __restrict__ bins, int4* __restrict__ lists,
    int* __restrict__ counts)
{
    const int b = blockIdx.y;
    const int k = blockIdx.x * BLOCK + threadIdx.x;
    const float bin0  = bins[0];
    const float invbw = 1.0f / (bins[1] - bin0);
    const bool valid = (k < N_);

    const float x = valid ? xs[b * N_ + k] : 3.0e30f;
    const float y = valid ? ys[b * N_ + k] : 3.0e30f;
    const float ux = (x - bin0) * invbw;
    const float uy = (y - bin0) * invbw;
    const float stx = rintf(ux) - 3.0f;      // window rows stx..stx+6
    const float sty = rintf(uy) - 3.0f;
    const float dx0 = ux - stx;              // in [2.5,3.5]
    const float dy0 = uy - sty;
    const int rx = (int)stx;
    const int ry = (int)sty;

    unsigned qx[7], qy[7];
    #pragma unroll
    for (int j = 0; j < 7; ++j) {
        const float dx = dx0 - (float)j;
        const float dy = dy0 - (float)j;
        qx[j] = (unsigned)(int)(EXP2(fmaf(-CS2 * dx, dx, L127)) + 0.5f) & 255u;
        qy[j] = (unsigned)(int)(EXP2(fmaf(-CS2 * dy, dy, L127)) + 0.5f) & 255u;
    }

    // membership: window rows rx..rx+6 intersect [ti*128, ti*128+128)?
    const bool mx[2] = { valid && rx >= -6  && rx <= 127,
                         valid && rx >= 122 && rx <= 255 };
    const bool my[2] = { valid && ry >= -6  && ry <= 127,
                         valid && ry >= 122 && ry <= 255 };

    const int lane = threadIdx.x & 63;
    #pragma unroll
    for (int ti = 0; ti < 2; ++ti) {
        #pragma unroll
        for (int tj = 0; tj < 2; ++tj) {
            const bool m = mx[ti] && my[tj];
            const unsigned long long mask = __ballot(m);
            if (mask) {                              // wave-uniform
                const int li = (b * 2 + ti) * 2 + tj;
                const int leader = __ffsll((unsigned long long)mask) - 1;
                int base = 0;
                if (lane == leader)
                    base = atomicAdd(&counts[li], __popcll(mask));
                base = __shfl(base, leader);
                if (m) {
                    const int off =
                        __popcll(mask & ((1ull << lane) - 1ull));
                    const unsigned rxl = (unsigned)(rx - ti * 128 + 8) & 255u;
                    const unsigned ryl = (unsigned)(ry - tj * 128 + 8) & 255u;
                    int4 e;
                    e.x = (int)(rxl | (ryl << 8) | (qx[0] << 16) | (qx[1] << 24));
                    e.y = (int)(qx[2] | (qx[3] << 8) | (qx[4] << 16) | (qx[5] << 24));
                    e.z = (int)(qx[6] | (qy[0] << 8) | (qy[1] << 16) | (qy[2] << 24));
                    e.w = (int)(qy[3] | (qy[4] << 8) | (qy[5] << 16) | (qy[6] << 24));
                    lists[(size_t)li * CAP + base + off] = e;
                }
            }
        }
    }
}

// ---- scatter one entry's half-window for one axis into the tile ----
// cbq = q*BUFB + axis*AXB + kcol (byte column base). ps = prev start row.
__device__ __forceinline__ void scat(char* __restrict__ tb, const int4 e,
                                     const int axis, const int h,
                                     const int cbq, int& ps)
{
    const int jbase = h << 2;
    const int dmp = cbq + 128 * LDKB;
    if (ps < (1 << 19)) {        // uniform: sentinel until first scatter
        const int pr = ps + jbase;
        tb[((unsigned)(pr    ) < 128u) ? (cbq + (pr    ) * LDKB) : dmp] = 0;
        tb[((unsigned)(pr + 1) < 128u) ? (cbq + (pr + 1) * LDKB) : dmp] = 0;
        tb[((unsigned)(pr + 2) < 128u) ? (cbq + (pr + 2) * LDKB) : dmp] = 0;
        if (!h)
            tb[((unsigned)(pr + 3) < 128u) ? (cbq + (pr + 3) * LDKB) : dmp] = 0;
    }
    const int rl = ((axis ? (e.x >> 8) : e.x) & 255) - 8;
    int q0, q1, q2, q3;
    if (axis == 0) {             // wave-uniform branch
        q0 = h ? ((e.y >> 16) & 255) : ((e.x >> 16) & 255);
        q1 = h ? (int)((unsigned)e.y >> 24) : (int)((unsigned)e.x >> 24);
        q2 = h ? (e.z & 255) : (e.y & 255);
        q3 = (e.y >> 8) & 255;
    } else {
        q0 = h ? ((e.w >> 8) & 255) : ((e.z >> 8) & 255);
        q1 = h ? ((e.w >> 16) & 255) : ((e.z >> 16) & 255);
        q2 = h ? (int)((unsigned)e.w >> 24) : (int)((unsigned)e.z >> 24);
        q3 = e.w & 255;
    }
    ps = rl;
    const int rr = rl + jbase;
    tb[((unsigned)(rr    ) < 128u) ? (cbq + (rr    ) * LDKB) : dmp] = (char)q0;
    tb[((unsigned)(rr + 1) < 128u) ? (cbq + (rr + 1) * LDKB) : dmp] = (char)q1;
    tb[((unsigned)(rr + 2) < 128u) ? (cbq + (rr + 2) * LDKB) : dmp] = (char)q2;
    if (!h)
        tb[((unsigned)(rr + 3) < 128u) ? (cbq + (rr + 3) * LDKB) : dmp] = (char)q3;
}

__global__ __launch_bounds__(BLOCK) void kde_gemm(
    const int4* __restrict__ lists, const int* __restrict__ counts,
    unsigned short* __restrict__ partial, float* __restrict__ ws2, int wide)
{
    __shared__ __align__(16) char tiles[2][2][ROWS][LDKB];  // 41280 B
    __shared__ float sred[4];

    const int tid   = threadIdx.x;
    const int tile  = blockIdx.x;            // ti = tile&1, tj = tile>>1
    const int chunk = blockIdx.y;
    const int b     = blockIdx.z;

    const int ti  = tile & 1;
    const int tj  = tile >> 1;
    const int ilo = ti * 128;
    const int jlo = tj * 128;

    const int li  = (b * 2 + ti) * 2 + tj;
    const int len = counts[li];
    const int seg = (len + NCH - 1) / NCH;
    const int start = chunk * seg;
    int myn = len - start;
    if (myn < 0) myn = 0;
    if (myn > seg) myn = seg;
    const int ksteps = (myn + 63) >> 6;      // <= 17 always
    const int4* lst = lists + (size_t)li * CAP + start;

    // ---- bulk-zero both buffers (incl. dump rows) ----
    {
        int4* za = (int4*)&tiles[0][0][0][0];
        const int4 z4 = {0, 0, 0, 0};
        for (int t = tid; t < (int)(sizeof(tiles) / 16); t += BLOCK) za[t] = z4;
    }

    // scatter role: lane PAIR within one wave owns a (kcol,axis) column
    const int h     = tid & 1;               // half-window (0: j0-3, 1: j4-6)
    const int kcol  = (tid >> 1) & 63;       // particle slot in K-step
    const int axis  = (tid >> 7) & 1;        // 0 -> kx tile, 1 -> ky tile
    const int colbase = axis * AXB + kcol;
    char* const tb = &tiles[0][0][0][0];

    // MFMA role: symmetric 64x64 quadrants
    const int w    = tid >> 6;
    const int R0   = (w >> 1) * 64;
    const int wj   = (w & 1) * 64;
    const int lane = tid & 63;
    const int lm   = lane & 15;
    const int quad = lane >> 4;
    unsigned short* pb = partial + (((size_t)chunk * B_ + b) << 16);

    i32x4 acc[4][4];
    #pragma unroll
    for (int mt = 0; mt < 4; ++mt)
        #pragma unroll
        for (int nt = 0; nt < 4; ++nt) acc[mt][nt] = i32x4{0, 0, 0, 0};

    int ps0 = 1 << 20, ps1 = 1 << 20;

    const int4 DUM = {0x0000FFFF, 0, 0, 0};  // rl=247 -> all rows clip to dump
    int4 e0 = DUM, enext = DUM;
    if (kcol < myn)      e0    = lst[kcol];
    if (BK + kcol < myn) enext = lst[BK + kcol];

    __syncthreads();                         // bulk zero complete

    if (ksteps > 0)                          // window 0 -> buf 0 (pre-zeroed)
        scat(tb, e0, axis, h, colbase, ps0);
    __syncthreads();

    for (int ks = 0; ks < ksteps; ++ks) {
        const int q = ks & 1;
        // prefetch window ks+2
        int4 epre = DUM;
        const int ka = (ks + 2) * BK + kcol;
        if ((ks + 2) < ksteps && ka < myn) epre = lst[ka];
        // scatter window ks+1 into buf q^1 (cleans own old cells)
        if ((ks + 1) < ksteps) {
            if (q) scat(tb, enext, axis, h, colbase, ps0);
            else   scat(tb, enext, axis, h, BUFB + colbase, ps1);
        }
        enext = epre;

        // consume buf q: K=64 in ONE mfma per frag-pair
        const char* bufA = tb + q * BUFB;
        const char* bufB = tb + q * BUFB + AXB;
        i32x4 af[4], bfr[4];
        #pragma unroll
        for (int t4 = 0; t4 < 4; ++t4)
            af[t4] = *(const i32x4*)(bufA + (R0 + t4 * 16 + lm) * LDKB + quad * 16);
        #pragma unroll
        for (int t4 = 0; t4 < 4; ++t4)
            bfr[t4] = *(const i32x4*)(bufB + (wj + t4 * 16 + lm) * LDKB + quad * 16);
        #pragma unroll
        for (int mt = 0; mt < 4; ++mt)
            #pragma unroll
            for (int nt = 0; nt < 4; ++nt)
                acc[mt][nt] = __builtin_amdgcn_mfma_i32_16x16x64_i8(
                    af[mt], bfr[nt], acc[mt][nt], 0, 0, 0);
        __syncthreads();                     // the only barrier per step
    }

    // ---- epilogue: bf16 split-K partial (C/D: col=lane&15, row=quad*4+e) ----
    float tsum = 0.f;
    #pragma unroll
    for (int mt = 0; mt < 4; ++mt) {
        const int row0 = ilo + R0 + mt * 16 + quad * 4;
        #pragma unroll
        for (int nt = 0; nt < 4; ++nt) {
            const int col = jlo + wj + nt * 16 + lm;
            const i32x4 a = acc[mt][nt];
            #pragma unroll
            for (int e = 0; e < 4; ++e) {
                const float v = (float)a[e];
                pb[(size_t)(row0 + e) * M_ + col] = bf16ru(v);
                tsum += v;
            }
        }
    }

    // ---- block sum -> ws2 ----
    #pragma unroll
    for (int off = 32; off; off >>= 1) tsum += __shfl_xor(tsum, off);
    if (lane == 0) sred[w] = tsum;
    __syncthreads();
    if (tid == 0) {
        const float bsum = sred[0] + sred[1] + sred[2] + sred[3];
        if (wide) {
            const int bid = (b * NCH + chunk) * 4 + tile;
            ws2[bid] = bsum;
        } else {
            atomicAdd(&ws2[b], bsum);
        }
    }
}

__global__ __launch_bounds__(BLOCK) void kde_tail(
    const unsigned short* __restrict__ partial, const float* __restrict__ ws2,
    float* __restrict__ out, int wide)
{
    __shared__ float sred[4];
    __shared__ float snorm;
    const int tid = threadIdx.x;
    const int cellIdx = blockIdx.x * BLOCK + tid;   // float4 index, 16384/batch
    const int bb = cellIdx >> 14;                   // uniform per block
    const int cb = cellIdx & 16383;

    float nrm;
    if (wide) {
        float t = (tid < 4 * NCH) ? ws2[bb * 4 * NCH + tid] : 0.f;
        #pragma unroll
        for (int off = 32; off; off >>= 1) t += __shfl_xor(t, off);
        if ((tid & 63) == 0) sred[tid >> 6] = t;
        __syncthreads();
        if (tid == 0) snorm = sred[0] + sred[1] + sred[2] + sred[3];
        __syncthreads();
        nrm = snorm;
    } else {
        nrm = ws2[bb];
    }

    float4 a = {0.f, 0.f, 0.f, 0.f};
    #pragma unroll 4
    for (int c = 0; c < NCH; ++c) {
        const ushort4 v = *(const ushort4*)(partial +
            (((size_t)c * B_ + bb) << 16) + (size_t)cb * 4);
        a.x += bf2f(v.x); a.y += bf2f(v.y); a.z += bf2f(v.z); a.w += bf2f(v.w);
    }
    const float sc = 1.0f / (nrm + 1e-10f);
    a.x *= sc; a.y *= sc; a.z *= sc; a.w *= sc;
    ((float4*)out)[cellIdx] = a;
}

extern "C" void kernel_launch(void* const* d_in, const int* in_sizes, int n_in,
                              void* d_out, int out_size, void* d_ws, size_t ws_size,
                              hipStream_t stream)
{
    const float* xs   = (const float*)d_in[0];
    const float* ys   = (const float*)d_in[1];
    const float* bins = (const float*)d_in[2];
    float* out = (float*)d_out;

    unsigned short* partial = (unsigned short*)d_ws;        // 24 MB bf16
    const size_t PSZ = (size_t)NCH * B_ * M_ * M_ * sizeof(unsigned short);
    float* ws2   = (float*)((char*)d_ws + PSZ);             // 768 f32 (wide)
    int*   counts = (int*)((char*)d_ws + PSZ + 4096);       // 16 ints
    int4*  lists  = (int4*)((char*)d_ws + PSZ + 8192);      // 16 MB

    const int wide = (ws_size >= PSZ + 4096) ? 1 : 0;
    if (!wide) hipMemsetAsync(ws2, 0, 4 * sizeof(float), stream);
    hipMemsetAsync(counts, 0, 16 * sizeof(int), stream);

    kde_bucket<<<dim3((N_ + BLOCK - 1) / BLOCK, B_), dim3(BLOCK), 0, stream>>>(
        xs, ys, bins, lists, counts);
    kde_gemm<<<dim3(4, NCH, B_), dim3(BLOCK), 0, stream>>>(
        lists, counts, partial, ws2, wide);
    kde_tail<<<dim3(B_ * M_ * M_ / (4 * BLOCK)), dim3(BLOCK), 0, stream>>>(
        partial, ws2, out, wide);
}

// Round 6
// 90.659 us; speedup vs baseline: 2.4956x; 2.4956x over previous
//
#include <hip/hip_runtime.h>

// KDE joint histogram, quadrant-compacted split-K INT8 MFMA GEMM (R16).
// joint[b,i,j] = sum_k kx[b,k,i]*ky[b,k,j]; q = round(127*exp(-0.5 d^2))
// (i8 support ±3.33 bins -> 7-bin window; 127^2 scale cancels in norm;
// i32 accumulation exact).
// Bucket pass compacts particles into per-(b,quadrant) lists with
// PRECOMPUTED quantized windows (16B/entry: rxl,ryl,qx[7],qy[7]);
// gemm K-depth per quadrant block drops 50000 -> ~14000 (KSTEPS 17 -> 5).
// R15 lesson: flat per-wave atomics on 16 counters in ONE cacheline =
// 145us of cross-XCD line ping-pong (VALUBusy 0.9%). R16: hierarchical
// counting — LDS aggregation per block, ONE global atomic per
// (block,quadrant), counters padded 128B apart, 49 blocks/batch.
// Earlier: R12 wider tile REGRESSED; R13 read-hoist+setprio REGRESSED;
// R14 balanced waves +2.1us. Clean/write same-column ordering in gemm is
// safe only because the h-split lane pair lives in ONE wave.

#define B_     4
#define N_     50000
#define M_     256
#define BK     64
#define NCH    48               // grid 4*48*4 = 768 = 3 blocks/CU (LDS 41.3KB)
#define LDKB   80               // tile row stride BYTES (16B-aligned)
#define ROWS   129              // 128 + dump row for clipped writes
#define AXB    (ROWS * LDKB)    // bytes per axis tile (10320)
#define BUFB   (2 * AXB)        // bytes per ping-pong buffer (20640)
#define BLOCK  256
#define CAP    65536            // entries per list (>= max possible N_)
#define NBB    49               // bucket blocks per batch: 49*4*256 >= N_
#define CPAD   32               // ints between counters (128B, own cacheline)
#define CS2    0.72134752f      // 0.5*log2(e)
#define L127   6.9886847f       // log2(127)

#if __has_builtin(__builtin_amdgcn_exp2f)
  #define EXP2(t) __builtin_amdgcn_exp2f(t)
#else
  #define EXP2(t) exp2f(t)
#endif

typedef __attribute__((ext_vector_type(4))) int i32x4;

__device__ __forceinline__ unsigned short bf16ru(float f) {  // round-half-up
    return (unsigned short)((__builtin_bit_cast(unsigned, f) + 0x8000u) >> 16);
}
__device__ __forceinline__ float bf2f(unsigned short u) {
    return __builtin_bit_cast(float, ((unsigned)u) << 16);
}

// ---- pass 0: bucket particles into quadrant lists, precompute windows ----
// Hierarchical: wave ballot -> LDS atomic (block-local bases) -> ONE global
// atomic per (block, quadrant) on padded counters -> positioned writes.
__global__ __launch_bounds__(BLOCK) void kde_bucket(
    const float* __restrict__ xs, const float* __restrict__ ys,
    const float* __restrict__ bins, int4* __restrict__ lists,
    int* __restrict__ counts)
{
    __shared__ int qcnt[4];
    __shared__ int qbase[4];

    const int b    = blockIdx.y;
    const int tid  = threadIdx.x;
    const int lane = tid & 63;
    if (tid < 4) qcnt[tid] = 0;
    __syncthreads();

    const float bin0  = bins[0];
    const float invbw = 1.0f / (bins[1] - bin0);

    float xv[4], yv[4];
    int   wb[4][4];              // per-round, per-quadrant wave base in block

    // ---- pass A: count (no exp2) ----
    #pragma unroll
    for (int r = 0; r < 4; ++r) {
        const int k = (blockIdx.x * 4 + r) * BLOCK + tid;
        const bool valid = (k < N_);
        const float x = valid ? xs[b * N_ + k] : 3.0e30f;
        const float y = valid ? ys[b * N_ + k] : 3.0e30f;
        xv[r] = x; yv[r] = y;
        const int rx = (int)(rintf((x - bin0) * invbw) - 3.0f);
        const int ry = (int)(rintf((y - bin0) * invbw) - 3.0f);
        const bool mx[2] = { rx >= -6 && rx <= 127, rx >= 122 && rx <= 255 };
        const bool my[2] = { ry >= -6 && ry <= 127, ry >= 122 && ry <= 255 };
        #pragma unroll
        for (int qd = 0; qd < 4; ++qd) {
            const bool m = mx[qd >> 1] && my[qd & 1];
            const unsigned long long mask = __ballot(m);
            int wbase = 0;
            if (mask) {
                const int leader = __ffsll(mask) - 1;
                int base0 = 0;
                if (lane == leader)
                    base0 = atomicAdd(&qcnt[qd], __popcll(mask));
                wbase = __shfl(base0, leader);
            }
            wb[r][qd] = wbase;
        }
    }
    __syncthreads();
    if (tid < 4)
        qbase[tid] = atomicAdd(&counts[(b * 4 + tid) * CPAD], qcnt[tid]);
    __syncthreads();

    // ---- pass B: compute windows, write positioned entries ----
    #pragma unroll
    for (int r = 0; r < 4; ++r) {
        const float x = xv[r], y = yv[r];
        const float ux = (x - bin0) * invbw;
        const float uy = (y - bin0) * invbw;
        const float stx = rintf(ux) - 3.0f;  // window rows stx..stx+6
        const float sty = rintf(uy) - 3.0f;
        const float dx0 = ux - stx;          // in [2.5,3.5]
        const float dy0 = uy - sty;
        const int rx = (int)stx;
        const int ry = (int)sty;

        unsigned qx[7], qy[7];
        #pragma unroll
        for (int j = 0; j < 7; ++j) {
            const float dx = dx0 - (float)j;
            const float dy = dy0 - (float)j;
            qx[j] = (unsigned)(int)(EXP2(fmaf(-CS2 * dx, dx, L127)) + 0.5f) & 255u;
            qy[j] = (unsigned)(int)(EXP2(fmaf(-CS2 * dy, dy, L127)) + 0.5f) & 255u;
        }
        const bool mx[2] = { rx >= -6 && rx <= 127, rx >= 122 && rx <= 255 };
        const bool my[2] = { ry >= -6 && ry <= 127, ry >= 122 && ry <= 255 };

        #pragma unroll
        for (int ti = 0; ti < 2; ++ti) {
            #pragma unroll
            for (int tj = 0; tj < 2; ++tj) {
                const int qd = ti * 2 + tj;
                const bool m = mx[ti] && my[tj];
                const unsigned long long mask = __ballot(m);
                if (m) {
                    const int off = __popcll(mask & ((1ull << lane) - 1ull));
                    const unsigned rxl = (unsigned)(rx - ti * 128 + 8) & 255u;
                    const unsigned ryl = (unsigned)(ry - tj * 128 + 8) & 255u;
                    int4 e;
                    e.x = (int)(rxl | (ryl << 8) | (qx[0] << 16) | (qx[1] << 24));
                    e.y = (int)(qx[2] | (qx[3] << 8) | (qx[4] << 16) | (qx[5] << 24));
                    e.z = (int)(qx[6] | (qy[0] << 8) | (qy[1] << 16) | (qy[2] << 24));
                    e.w = (int)(qy[3] | (qy[4] << 8) | (qy[5] << 16) | (qy[6] << 24));
                    lists[(size_t)(b * 4 + qd) * CAP +
                          qbase[qd] + wb[r][qd] + off] = e;
                }
            }
        }
    }
}

// ---- scatter one entry's half-window for one axis into the tile ----
// cbq = q*BUFB + axis*AXB + kcol (byte column base). ps = prev start row.
__device__ __forceinline__ void scat(char* __restrict__ tb, const int4 e,
                                     const int axis, const int h,
                                     const int cbq, int& ps)
{
    const int jbase = h << 2;
    const int dmp = cbq + 128 * LDKB;
    if (ps < (1 << 19)) {        // uniform: sentinel until first scatter
        const int pr = ps + jbase;
        tb[((unsigned)(pr    ) < 128u) ? (cbq + (pr    ) * LDKB) : dmp] = 0;
        tb[((unsigned)(pr + 1) < 128u) ? (cbq + (pr + 1) * LDKB) : dmp] = 0;
        tb[((unsigned)(pr + 2) < 128u) ? (cbq + (pr + 2) * LDKB) : dmp] = 0;
        if (!h)
            tb[((unsigned)(pr + 3) < 128u) ? (cbq + (pr + 3) * LDKB) : dmp] = 0;
    }
    const int rl = ((axis ? (e.x >> 8) : e.x) & 255) - 8;
    int q0, q1, q2, q3;
    if (axis == 0) {             // wave-uniform branch
        q0 = h ? ((e.y >> 16) & 255) : ((e.x >> 16) & 255);
        q1 = h ? (int)((unsigned)e.y >> 24) : (int)((unsigned)e.x >> 24);
        q2 = h ? (e.z & 255) : (e.y & 255);
        q3 = (e.y >> 8) & 255;
    } else {
        q0 = h ? ((e.w >> 8) & 255) : ((e.z >> 8) & 255);
        q1 = h ? ((e.w >> 16) & 255) : ((e.z >> 16) & 255);
        q2 = h ? (int)((unsigned)e.w >> 24) : (int)((unsigned)e.z >> 24);
        q3 = e.w & 255;
    }
    ps = rl;
    const int rr = rl + jbase;
    tb[((unsigned)(rr    ) < 128u) ? (cbq + (rr    ) * LDKB) : dmp] = (char)q0;
    tb[((unsigned)(rr + 1) < 128u) ? (cbq + (rr + 1) * LDKB) : dmp] = (char)q1;
    tb[((unsigned)(rr + 2) < 128u) ? (cbq + (rr + 2) * LDKB) : dmp] = (char)q2;
    if (!h)
        tb[((unsigned)(rr + 3) < 128u) ? (cbq + (rr + 3) * LDKB) : dmp] = (char)q3;
}

__global__ __launch_bounds__(BLOCK) void kde_gemm(
    const int4* __restrict__ lists, const int* __restrict__ counts,
    unsigned short* __restrict__ partial, float* __restrict__ ws2, int wide)
{
    __shared__ __align__(16) char tiles[2][2][ROWS][LDKB];  // 41280 B
    __shared__ float sred[4];

    const int tid   = threadIdx.x;
    const int tile  = blockIdx.x;            // ti = tile&1, tj = tile>>1
    const int chunk = blockIdx.y;
    const int b     = blockIdx.z;

    const int ti  = tile & 1;
    const int tj  = tile >> 1;
    const int ilo = ti * 128;
    const int jlo = tj * 128;

    const int li  = (b * 2 + ti) * 2 + tj;
    const int len = counts[li * CPAD];
    const int seg = (len + NCH - 1) / NCH;
    const int start = chunk * seg;
    int myn = len - start;
    if (myn < 0) myn = 0;
    if (myn > seg) myn = seg;
    const int ksteps = (myn + 63) >> 6;      // <= 17 always
    const int4* lst = lists + (size_t)li * CAP + start;

    // ---- bulk-zero both buffers (incl. dump rows) ----
    {
        int4* za = (int4*)&tiles[0][0][0][0];
        const int4 z4 = {0, 0, 0, 0};
        for (int t = tid; t < (int)(sizeof(tiles) / 16); t += BLOCK) za[t] = z4;
    }

    // scatter role: lane PAIR within one wave owns a (kcol,axis) column
    const int h     = tid & 1;               // half-window (0: j0-3, 1: j4-6)
    const int kcol  = (tid >> 1) & 63;       // particle slot in K-step
    const int axis  = (tid >> 7) & 1;        // 0 -> kx tile, 1 -> ky tile
    const int colbase = axis * AXB + kcol;
    char* const tb = &tiles[0][0][0][0];

    // MFMA role: symmetric 64x64 quadrants
    const int w    = tid >> 6;
    const int R0   = (w >> 1) * 64;
    const int wj   = (w & 1) * 64;
    const int lane = tid & 63;
    const int lm   = lane & 15;
    const int quad = lane >> 4;
    unsigned short* pb = partial + (((size_t)chunk * B_ + b) << 16);

    i32x4 acc[4][4];
    #pragma unroll
    for (int mt = 0; mt < 4; ++mt)
        #pragma unroll
        for (int nt = 0; nt < 4; ++nt) acc[mt][nt] = i32x4{0, 0, 0, 0};

    int ps0 = 1 << 20, ps1 = 1 << 20;

    const int4 DUM = {0x0000FFFF, 0, 0, 0};  // rl=247 -> all rows clip to dump
    int4 e0 = DUM, enext = DUM;
    if (kcol < myn)      e0    = lst[kcol];
    if (BK + kcol < myn) enext = lst[BK + kcol];

    __syncthreads();                         // bulk zero complete

    if (ksteps > 0)                          // window 0 -> buf 0 (pre-zeroed)
        scat(tb, e0, axis, h, colbase, ps0);
    __syncthreads();

    for (int ks = 0; ks < ksteps; ++ks) {
        const int q = ks & 1;
        // prefetch window ks+2
        int4 epre = DUM;
        const int ka = (ks + 2) * BK + kcol;
        if ((ks + 2) < ksteps && ka < myn) epre = lst[ka];
        // scatter window ks+1 into buf q^1 (cleans own old cells)
        if ((ks + 1) < ksteps) {
            if (q) scat(tb, enext, axis, h, colbase, ps0);
            else   scat(tb, enext, axis, h, BUFB + colbase, ps1);
        }
        enext = epre;

        // consume buf q: K=64 in ONE mfma per frag-pair
        const char* bufA = tb + q * BUFB;
        const char* bufB = tb + q * BUFB + AXB;
        i32x4 af[4], bfr[4];
        #pragma unroll
        for (int t4 = 0; t4 < 4; ++t4)
            af[t4] = *(const i32x4*)(bufA + (R0 + t4 * 16 + lm) * LDKB + quad * 16);
        #pragma unroll
        for (int t4 = 0; t4 < 4; ++t4)
            bfr[t4] = *(const i32x4*)(bufB + (wj + t4 * 16 + lm) * LDKB + quad * 16);
        #pragma unroll
        for (int mt = 0; mt < 4; ++mt)
            #pragma unroll
            for (int nt = 0; nt < 4; ++nt)
                acc[mt][nt] = __builtin_amdgcn_mfma_i32_16x16x64_i8(
                    af[mt], bfr[nt], acc[mt][nt], 0, 0, 0);
        __syncthreads();                     // the only barrier per step
    }

    // ---- epilogue: bf16 split-K partial (C/D: col=lane&15, row=quad*4+e) ----
    float tsum = 0.f;
    #pragma unroll
    for (int mt = 0; mt < 4; ++mt) {
        const int row0 = ilo + R0 + mt * 16 + quad * 4;
        #pragma unroll
        for (int nt = 0; nt < 4; ++nt) {
            const int col = jlo + wj + nt * 16 + lm;
            const i32x4 a = acc[mt][nt];
            #pragma unroll
            for (int e = 0; e < 4; ++e) {
                const float v = (float)a[e];
                pb[(size_t)(row0 + e) * M_ + col] = bf16ru(v);
                tsum += v;
            }
        }
    }

    // ---- block sum -> ws2 ----
    #pragma unroll
    for (int off = 32; off; off >>= 1) tsum += __shfl_xor(tsum, off);
    if (lane == 0) sred[w] = tsum;
    __syncthreads();
    if (tid == 0) {
        const float bsum = sred[0] + sred[1] + sred[2] + sred[3];
        if (wide) {
            const int bid = (b * NCH + chunk) * 4 + tile;
            ws2[bid] = bsum;
        } else {
            atomicAdd(&ws2[b], bsum);
        }
    }
}

__global__ __launch_bounds__(BLOCK) void kde_tail(
    const unsigned short* __restrict__ partial, const float* __restrict__ ws2,
    float* __restrict__ out, int wide)
{
    __shared__ float sred[4];
    __shared__ float snorm;
    const int tid = threadIdx.x;
    const int cellIdx = blockIdx.x * BLOCK + tid;   // float4 index, 16384/batch
    const int bb = cellIdx >> 14;                   // uniform per block
    const int cb = cellIdx & 16383;

    float nrm;
    if (wide) {
        float t = (tid < 4 * NCH) ? ws2[bb * 4 * NCH + tid] : 0.f;
        #pragma unroll
        for (int off = 32; off; off >>= 1) t += __shfl_xor(t, off);
        if ((tid & 63) == 0) sred[tid >> 6] = t;
        __syncthreads();
        if (tid == 0) snorm = sred[0] + sred[1] + sred[2] + sred[3];
        __syncthreads();
        nrm = snorm;
    } else {
        nrm = ws2[bb];
    }

    float4 a = {0.f, 0.f, 0.f, 0.f};
    #pragma unroll 4
    for (int c = 0; c < NCH; ++c) {
        const ushort4 v = *(const ushort4*)(partial +
            (((size_t)c * B_ + bb) << 16) + (size_t)cb * 4);
        a.x += bf2f(v.x); a.y += bf2f(v.y); a.z += bf2f(v.z); a.w += bf2f(v.w);
    }
    const float sc = 1.0f / (nrm + 1e-10f);
    a.x *= sc; a.y *= sc; a.z *= sc; a.w *= sc;
    ((float4*)out)[cellIdx] = a;
}

extern "C" void kernel_launch(void* const* d_in, const int* in_sizes, int n_in,
                              void* d_out, int out_size, void* d_ws, size_t ws_size,
                              hipStream_t stream)
{
    const float* xs   = (const float*)d_in[0];
    const float* ys   = (const float*)d_in[1];
    const float* bins = (const float*)d_in[2];
    float* out = (float*)d_out;

    unsigned short* partial = (unsigned short*)d_ws;        // 24 MB bf16
    const size_t PSZ = (size_t)NCH * B_ * M_ * M_ * sizeof(unsigned short);
    float* ws2   = (float*)((char*)d_ws + PSZ);             // 768 f32 (wide)
    int*   counts = (int*)((char*)d_ws + PSZ + 4096);       // 16 x CPAD ints
    int4*  lists  = (int4*)((char*)d_ws + PSZ + 8192);      // 16 MB

    const int wide = (ws_size >= PSZ + 4096) ? 1 : 0;
    if (!wide) hipMemsetAsync(ws2, 0, 4 * sizeof(float), stream);
    hipMemsetAsync(counts, 0, 16 * CPAD * sizeof(int), stream);

    kde_bucket<<<dim3(NBB, B_), dim3(BLOCK), 0, stream>>>(
        xs, ys, bins, lists, counts);
    kde_gemm<<<dim3(4, NCH, B_), dim3(BLOCK), 0, stream>>>(
        lists, counts, partial, ws2, wide);
    kde_tail<<<dim3(B_ * M_ * M_ / (4 * BLOCK)), dim3(BLOCK), 0, stream>>>(
        partial, ws2, out, wide);
}

// Round 7
// 81.626 us; speedup vs baseline: 2.7717x; 1.1107x over previous
//
#include <hip/hip_runtime.h>

// KDE joint histogram via DIRECT LDS SCATTER-ACCUMULATE (R17).
// joint[b,i,j] = sum_k qx[b,k,i]*qy[b,k,j], q = round(127*exp(-0.5 d^2))
// (i8 support ±3.33 bins -> 7-bin window; 127^2 scale cancels in norm).
// Real work is only 200K particles x 49 cells = ~10M int MACs — the MFMA
// GEMM formulation (R11-R16) multiplied 99.9% zeros and carried ~16us of
// fixed staging/partial machinery plus a 10us bucket pass. R17: each block
// owns a 128x256 output strip as an i32 LDS grid (128KB, 1 block/CU) and
// scans a raw K-chunk, doing 49 ds_add_u32 per intersecting particle
// (exec-mask skips non-intersecting lanes). No bucket, no lists, fewer
// launches. Integer atomics commute -> partials DETERMINISTIC, quantization
// identical to R14/R16 -> same accuracy. bf16 partial + tail as before.
// Lessons: R12 wider tile REGRESSED; R13 read-hoist+setprio REGRESSED;
// R15 single-cacheline global atomics = 145us (cross-XCD ping-pong);
// R16 sparse-GEMM net-neutral vs dense (fixed costs dominate).

#define B_     4
#define N_     50000
#define M_     256
#define NCH    32                  // raw-K chunks (split-K partials)
#define NST    2                   // strips of 128 output rows
#define CHUNK  ((N_ + NCH - 1) / NCH)   // 1563
#define BLOCK  256
#define GROWS  128
#define GCELLS (GROWS * M_)        // 32768 live cells
#define GSZ    33088               // + dump scratch (max addr 32768+63+255)
#define CS2    0.72134752f         // 0.5*log2(e)
#define L127   6.9886847f          // log2(127)

#if __has_builtin(__builtin_amdgcn_exp2f)
  #define EXP2(t) __builtin_amdgcn_exp2f(t)
#else
  #define EXP2(t) exp2f(t)
#endif

__device__ __forceinline__ unsigned short bf16ru(float f) {  // round-half-up
    return (unsigned short)((__builtin_bit_cast(unsigned, f) + 0x8000u) >> 16);
}
__device__ __forceinline__ float bf2f(unsigned short u) {
    return __builtin_bit_cast(float, ((unsigned)u) << 16);
}

__global__ __launch_bounds__(BLOCK) void kde_accum(
    const float* __restrict__ xs, const float* __restrict__ ys,
    const float* __restrict__ bins, unsigned short* __restrict__ partial,
    float* __restrict__ ws2, int wide)
{
    __shared__ __align__(16) unsigned int G[GSZ];   // 132,352 B -> 1 block/CU
    __shared__ float sred[4];

    const int tid   = threadIdx.x;
    const int strip = blockIdx.x;          // 0..NST-1: rows [strip*128, +128)
    const int chunk = blockIdx.y;          // 0..NCH-1: raw K segment
    const int b     = blockIdx.z;
    const int lane  = tid & 63;
    const int w     = tid >> 6;

    const float bin0  = bins[0];
    const float invbw = 1.0f / (bins[1] - bin0);
    const int   rlo   = strip * GROWS;

    // ---- zero the grid (incl. dump scratch) ----
    {
        uint4* gz = (uint4*)G;
        const uint4 z4 = {0u, 0u, 0u, 0u};
        for (int t = tid; t < GSZ / 4; t += BLOCK) gz[t] = z4;
    }
    __syncthreads();

    const int start = chunk * CHUNK;
    const int end   = (start + CHUNK < N_) ? (start + CHUNK) : N_;
    const float* xp = xs + (size_t)b * N_;
    const float* yp = ys + (size_t)b * N_;

    const unsigned dmp = (unsigned)(GCELLS + lane);  // per-lane dump (no same-addr pileup)

    // software-pipelined particle loop (prefetch next round's coords)
    int k = start + tid;
    float x = 3.0e30f, y = 3.0e30f;
    if (k < end) { x = xp[k]; y = yp[k]; }
    for (; k < end; k += BLOCK) {
        float xn = 3.0e30f, yn = 3.0e30f;
        if (k + BLOCK < end) { xn = xp[k + BLOCK]; yn = yp[k + BLOCK]; }

        const float ux  = (x - bin0) * invbw;
        const float uy  = (y - bin0) * invbw;
        const float stx = rintf(ux) - 3.0f;      // window rows rx..rx+6
        const float sty = rintf(uy) - 3.0f;
        const int rx = (int)stx;
        const int ry = (int)sty;

        // active iff x-window intersects this strip AND y-window hits grid
        if (rx + 6 >= rlo && rx < rlo + GROWS && ry + 6 >= 0 && ry < M_) {
            const float dx0 = ux - stx;          // in [2.5, 3.5]
            const float dy0 = uy - sty;
            unsigned qx[7], qy[7], cofs[7];
            #pragma unroll
            for (int j = 0; j < 7; ++j) {
                const float dx = dx0 - (float)j;
                const float dy = dy0 - (float)j;
                qx[j] = (unsigned)(int)(EXP2(fmaf(-CS2 * dx, dx, L127)) + 0.5f);
                qy[j] = (unsigned)(int)(EXP2(fmaf(-CS2 * dy, dy, L127)) + 0.5f);
                const int c = ry + j;
                // valid col -> col index; invalid -> high-bit marker
                cofs[j] = ((unsigned)c < (unsigned)M_) ? (unsigned)c : 0x80000000u;
            }
            #pragma unroll
            for (int i = 0; i < 7; ++i) {
                const int rr = rx + i - rlo;
                const unsigned rbase =
                    ((unsigned)rr < (unsigned)GROWS) ? (unsigned)(rr << 8) : dmp;
                const unsigned wxi = qx[i];
                #pragma unroll
                for (int j = 0; j < 7; ++j) {
                    unsigned addr = rbase + cofs[j];
                    addr = ((int)addr < 0) ? dmp : addr;   // col-invalid -> dump
                    atomicAdd(&G[addr], wxi * qy[j]);      // ds_add_u32, no-return
                }
            }
        }
        x = xn; y = yn;
    }
    __syncthreads();                         // all waves' atomics complete

    // ---- epilogue: i32 grid -> bf16 split-K partial + strip sum ----
    unsigned short* pb = partial + (((size_t)chunk * B_ + b) << 16);
    float tsum = 0.f;
    #pragma unroll
    for (int rep = 0; rep < GCELLS / (BLOCK * 4); ++rep) {   // 32 reps
        const int cell = rep * (BLOCK * 4) + tid * 4;
        const uint4 gv = *(const uint4*)&G[cell];            // ds_read_b128
        const float f0 = (float)gv.x, f1 = (float)gv.y;
        const float f2 = (float)gv.z, f3 = (float)gv.w;
        tsum += (f0 + f1) + (f2 + f3);
        ushort4 o;
        o.x = bf16ru(f0); o.y = bf16ru(f1); o.z = bf16ru(f2); o.w = bf16ru(f3);
        const int r = cell >> 8;             // strip-local row
        const int c = cell & (M_ - 1);       // col (multiple of 4)
        *(ushort4*)&pb[(size_t)(rlo + r) * M_ + c] = o;
    }

    // ---- block sum -> ws2 ----
    #pragma unroll
    for (int off = 32; off; off >>= 1) tsum += __shfl_xor(tsum, off);
    if (lane == 0) sred[w] = tsum;
    __syncthreads();
    if (tid == 0) {
        const float bsum = sred[0] + sred[1] + sred[2] + sred[3];
        if (wide) {
            const int bid = (b * NCH + chunk) * NST + strip;   // < 256
            ws2[bid] = bsum;
        } else {
            atomicAdd(&ws2[b], bsum);
        }
    }
}

__global__ __launch_bounds__(BLOCK) void kde_tail(
    const unsigned short* __restrict__ partial, const float* __restrict__ ws2,
    float* __restrict__ out, int wide)
{
    __shared__ float sred[4];
    __shared__ float snorm;
    const int tid = threadIdx.x;
    const int cellIdx = blockIdx.x * BLOCK + tid;   // float4 index, 16384/batch
    const int bb = cellIdx >> 14;                   // uniform per block
    const int cb = cellIdx & 16383;

    float nrm;
    if (wide) {
        float t = (tid < NCH * NST) ? ws2[bb * (NCH * NST) + tid] : 0.f;
        #pragma unroll
        for (int off = 32; off; off >>= 1) t += __shfl_xor(t, off);
        if ((tid & 63) == 0) sred[tid >> 6] = t;
        __syncthreads();
        if (tid == 0) snorm = sred[0] + sred[1] + sred[2] + sred[3];
        __syncthreads();
        nrm = snorm;
    } else {
        nrm = ws2[bb];
    }

    float4 a = {0.f, 0.f, 0.f, 0.f};
    #pragma unroll 4
    for (int c = 0; c < NCH; ++c) {
        const ushort4 v = *(const ushort4*)(partial +
            (((size_t)c * B_ + bb) << 16) + (size_t)cb * 4);
        a.x += bf2f(v.x); a.y += bf2f(v.y); a.z += bf2f(v.z); a.w += bf2f(v.w);
    }
    // i8 scale (127^2) cancels: both partials and nrm carry it.
    const float sc = 1.0f / (nrm + 1e-10f);
    a.x *= sc; a.y *= sc; a.z *= sc; a.w *= sc;
    ((float4*)out)[cellIdx] = a;
}

extern "C" void kernel_launch(void* const* d_in, const int* in_sizes, int n_in,
                              void* d_out, int out_size, void* d_ws, size_t ws_size,
                              hipStream_t stream)
{
    const float* xs   = (const float*)d_in[0];
    const float* ys   = (const float*)d_in[1];
    const float* bins = (const float*)d_in[2];
    float* out = (float*)d_out;

    unsigned short* partial = (unsigned short*)d_ws;        // 16.8 MB bf16
    const size_t PSZ = (size_t)NCH * B_ * M_ * M_ * sizeof(unsigned short);
    float* ws2 = (float*)((char*)d_ws + PSZ);               // 256 f32 (wide)

    const int wide = (ws_size >= PSZ + 4096) ? 1 : 0;
    if (!wide) hipMemsetAsync(ws2, 0, 4 * sizeof(float), stream);

    kde_accum<<<dim3(NST, NCH, B_), dim3(BLOCK), 0, stream>>>(
        xs, ys, bins, partial, ws2, wide);
    kde_tail<<<dim3(B_ * M_ * M_ / (4 * BLOCK)), dim3(BLOCK), 0, stream>>>(
        partial, ws2, out, wide);
}

// Round 8
// 75.814 us; speedup vs baseline: 2.9842x; 1.0767x over previous
//
#include <hip/hip_runtime.h>

// KDE joint histogram via DIRECT LDS SCATTER-ACCUMULATE (R18).
// joint[b,i,j] = sum_k qx[b,k,i]*qy[b,k,j], q = round(127*exp(-0.5 d^2))
// (i8 support ±3.33 bins -> 7-bin window; 127^2 scale cancels in norm).
// Each block owns a 128x256 output strip as an i32 LDS grid (128KB) and
// scans a raw K-chunk, doing 49 ds_add_u32 per intersecting particle.
// Integer atomics commute -> partials DETERMINISTIC; quantization identical
// to R14-R17. bf16 split-K partial + tail reduce.
// R17 lesson: BLOCK=256 at 128KB LDS = 1 wave/SIMD — zero latency hiding;
// accum ran ~28us vs ~8 modeled. R18: BLOCK=1024 -> 16 waves/CU at the
// same 1 block/CU (LDS-limited). Same total DS work, 4x the TLP.
// Earlier: R12 wider tile REGRESSED; R13 read-hoist+setprio REGRESSED;
// R15 single-cacheline global atomics = 145us cross-XCD ping-pong;
// R16 sparse-GEMM net-neutral (fixed costs); R17 reformulation -9us.

#define B_     4
#define N_     50000
#define M_     256
#define NCH    32                  // raw-K chunks (split-K partials)
#define NST    2                   // strips of 128 output rows
#define CHUNK  ((N_ + NCH - 1) / NCH)   // 1563
#define BLOCK  1024                // 16 waves/CU (1 block/CU, LDS-limited)
#define NWAVE  (BLOCK / 64)
#define GROWS  128
#define GCELLS (GROWS * M_)        // 32768 live cells
#define GSZ    33088               // + dump scratch (max addr 32768+63+255)
#define CS2    0.72134752f         // 0.5*log2(e)
#define L127   6.9886847f          // log2(127)

#if __has_builtin(__builtin_amdgcn_exp2f)
  #define EXP2(t) __builtin_amdgcn_exp2f(t)
#else
  #define EXP2(t) exp2f(t)
#endif

__device__ __forceinline__ unsigned short bf16ru(float f) {  // round-half-up
    return (unsigned short)((__builtin_bit_cast(unsigned, f) + 0x8000u) >> 16);
}
__device__ __forceinline__ float bf2f(unsigned short u) {
    return __builtin_bit_cast(float, ((unsigned)u) << 16);
}

__global__ __launch_bounds__(BLOCK) void kde_accum(
    const float* __restrict__ xs, const float* __restrict__ ys,
    const float* __restrict__ bins, unsigned short* __restrict__ partial,
    float* __restrict__ ws2, int wide)
{
    __shared__ __align__(16) unsigned int G[GSZ];   // 132,352 B -> 1 block/CU
    __shared__ float sred[NWAVE];

    const int tid   = threadIdx.x;
    const int strip = blockIdx.x;          // 0..NST-1: rows [strip*128, +128)
    const int chunk = blockIdx.y;          // 0..NCH-1: raw K segment
    const int b     = blockIdx.z;
    const int lane  = tid & 63;
    const int w     = tid >> 6;

    const float bin0  = bins[0];
    const float invbw = 1.0f / (bins[1] - bin0);
    const int   rlo   = strip * GROWS;

    // ---- zero the grid (incl. dump scratch) ----
    {
        uint4* gz = (uint4*)G;
        const uint4 z4 = {0u, 0u, 0u, 0u};
        for (int t = tid; t < GSZ / 4; t += BLOCK) gz[t] = z4;
    }
    __syncthreads();

    const int start = chunk * CHUNK;
    const int end   = (start + CHUNK < N_) ? (start + CHUNK) : N_;
    const float* xp = xs + (size_t)b * N_;
    const float* yp = ys + (size_t)b * N_;

    const unsigned dmp = (unsigned)(GCELLS + lane);  // per-lane dump (no pileup)

    // software-pipelined particle loop (prefetch next round's coords)
    int k = start + tid;
    float x = 3.0e30f, y = 3.0e30f;
    if (k < end) { x = xp[k]; y = yp[k]; }
    for (; k < end; k += BLOCK) {
        float xn = 3.0e30f, yn = 3.0e30f;
        if (k + BLOCK < end) { xn = xp[k + BLOCK]; yn = yp[k + BLOCK]; }

        const float ux  = (x - bin0) * invbw;
        const float uy  = (y - bin0) * invbw;
        const float stx = rintf(ux) - 3.0f;      // window rows rx..rx+6
        const float sty = rintf(uy) - 3.0f;
        const int rx = (int)stx;
        const int ry = (int)sty;

        // active iff x-window intersects this strip AND y-window hits grid
        if (rx + 6 >= rlo && rx < rlo + GROWS && ry + 6 >= 0 && ry < M_) {
            const float dx0 = ux - stx;          // in [2.5, 3.5]
            const float dy0 = uy - sty;
            unsigned qx[7], qy[7], cofs[7];
            #pragma unroll
            for (int j = 0; j < 7; ++j) {
                const float dx = dx0 - (float)j;
                const float dy = dy0 - (float)j;
                qx[j] = (unsigned)(int)(EXP2(fmaf(-CS2 * dx, dx, L127)) + 0.5f);
                qy[j] = (unsigned)(int)(EXP2(fmaf(-CS2 * dy, dy, L127)) + 0.5f);
                const int c = ry + j;
                // valid col -> col index; invalid -> high-bit marker
                cofs[j] = ((unsigned)c < (unsigned)M_) ? (unsigned)c : 0x80000000u;
            }
            #pragma unroll
            for (int i = 0; i < 7; ++i) {
                const int rr = rx + i - rlo;
                const unsigned rbase =
                    ((unsigned)rr < (unsigned)GROWS) ? (unsigned)(rr << 8) : dmp;
                const unsigned wxi = qx[i];
                #pragma unroll
                for (int j = 0; j < 7; ++j) {
                    unsigned addr = rbase + cofs[j];
                    addr = ((int)addr < 0) ? dmp : addr;   // col-invalid -> dump
                    atomicAdd(&G[addr], wxi * qy[j]);      // ds_add_u32, no-return
                }
            }
        }
        x = xn; y = yn;
    }
    __syncthreads();                         // all waves' atomics complete

    // ---- epilogue: i32 grid -> bf16 split-K partial + strip sum ----
    unsigned short* pb = partial + (((size_t)chunk * B_ + b) << 16);
    float tsum = 0.f;
    #pragma unroll
    for (int rep = 0; rep < GCELLS / (BLOCK * 4); ++rep) {   // 8 reps
        const int cell = rep * (BLOCK * 4) + tid * 4;
        const uint4 gv = *(const uint4*)&G[cell];            // ds_read_b128
        const float f0 = (float)gv.x, f1 = (float)gv.y;
        const float f2 = (float)gv.z, f3 = (float)gv.w;
        tsum += (f0 + f1) + (f2 + f3);
        ushort4 o;
        o.x = bf16ru(f0); o.y = bf16ru(f1); o.z = bf16ru(f2); o.w = bf16ru(f3);
        const int r = cell >> 8;             // strip-local row
        const int c = cell & (M_ - 1);       // col (multiple of 4)
        *(ushort4*)&pb[(size_t)(rlo + r) * M_ + c] = o;
    }

    // ---- block sum -> ws2 ----
    #pragma unroll
    for (int off = 32; off; off >>= 1) tsum += __shfl_xor(tsum, off);
    if (lane == 0) sred[w] = tsum;
    __syncthreads();
    if (tid == 0) {
        float bsum = 0.f;
        #pragma unroll
        for (int i = 0; i < NWAVE; ++i) bsum += sred[i];
        if (wide) {
            const int bid = (b * NCH + chunk) * NST + strip;   // < 256
            ws2[bid] = bsum;
        } else {
            atomicAdd(&ws2[b], bsum);
        }
    }
}

__global__ __launch_bounds__(256) void kde_tail(
    const unsigned short* __restrict__ partial, const float* __restrict__ ws2,
    float* __restrict__ out, int wide)
{
    __shared__ float sred[4];
    __shared__ float snorm;
    const int tid = threadIdx.x;
    const int cellIdx = blockIdx.x * 256 + tid;     // float4 index, 16384/batch
    const int bb = cellIdx >> 14;                   // uniform per block
    const int cb = cellIdx & 16383;

    float nrm;
    if (wide) {
        float t = (tid < NCH * NST) ? ws2[bb * (NCH * NST) + tid] : 0.f;
        #pragma unroll
        for (int off = 32; off; off >>= 1) t += __shfl_xor(t, off);
        if ((tid & 63) == 0) sred[tid >> 6] = t;
        __syncthreads();
        if (tid == 0) snorm = sred[0] + sred[1] + sred[2] + sred[3];
        __syncthreads();
        nrm = snorm;
    } else {
        nrm = ws2[bb];
    }

    float4 a = {0.f, 0.f, 0.f, 0.f};
    #pragma unroll 4
    for (int c = 0; c < NCH; ++c) {
        const ushort4 v = *(const ushort4*)(partial +
            (((size_t)c * B_ + bb) << 16) + (size_t)cb * 4);
        a.x += bf2f(v.x); a.y += bf2f(v.y); a.z += bf2f(v.z); a.w += bf2f(v.w);
    }
    // i8 scale (127^2) cancels: both partials and nrm carry it.
    const float sc = 1.0f / (nrm + 1e-10f);
    a.x *= sc; a.y *= sc; a.z *= sc; a.w *= sc;
    ((float4*)out)[cellIdx] = a;
}

extern "C" void kernel_launch(void* const* d_in, const int* in_sizes, int n_in,
                              void* d_out, int out_size, void* d_ws, size_t ws_size,
                              hipStream_t stream)
{
    const float* xs   = (const float*)d_in[0];
    const float* ys   = (const float*)d_in[1];
    const float* bins = (const float*)d_in[2];
    float* out = (float*)d_out;

    unsigned short* partial = (unsigned short*)d_ws;        // 16.8 MB bf16
    const size_t PSZ = (size_t)NCH * B_ * M_ * M_ * sizeof(unsigned short);
    float* ws2 = (float*)((char*)d_ws + PSZ);               // 256 f32 (wide)

    const int wide = (ws_size >= PSZ + 4096) ? 1 : 0;
    if (!wide) hipMemsetAsync(ws2, 0, 4 * sizeof(float), stream);

    kde_accum<<<dim3(NST, NCH, B_), dim3(BLOCK), 0, stream>>>(
        xs, ys, bins, partial, ws2, wide);
    kde_tail<<<dim3(B_ * M_ * M_ / (4 * 256)), dim3(256), 0, stream>>>(
        partial, ws2, out, wide);
}

// Round 9
// 75.112 us; speedup vs baseline: 3.0121x; 1.0094x over previous
//
#include <hip/hip_runtime.h>

// KDE joint histogram via DIRECT LDS SCATTER-ACCUMULATE (R19).
// joint[b,i,j] = sum_k qx[b,k,i]*qy[b,k,j], q = round(127*exp(-0.5 d^2))
// (i8 support ±3.33 bins -> 7-bin window; 127^2 scale cancels in norm).
// Each block owns a 128x256 output strip as an i32 LDS grid and scans a raw
// K-chunk. R19: column-PAIR packed ds_add_u64 atomics — 28 per particle
// instead of 49 ds_add_u32. Safe because: grid width 256 is even and pairs
// are even-aligned (pairs fully valid or fully invalid, never split), and
// per-block per-cell sums <= 1563*127^2 ~ 25M < 2^31 so the 32-bit halves
// can never carry into each other. wxi*(lo|hi<<32) = (wxi*lo)|(wxi*hi)<<32
// exactly (each product < 2^31) -> one u64 mad per pair. Accumulation
// bit-identical to R17/R18.
// R17 lesson: 128KB LDS + BLOCK=256 = 1 wave/SIMD, zero latency hiding.
// R18 lesson: BLOCK=1024 (16 waves/CU) -> -5.8us; accum still ~24us ==
// DS-atomic-pipe throughput bound (random-bank RMW ~15-25cyc each).
// Earlier: R15 single-cacheline global atomics = 145us cross-XCD ping-pong;
// R16 sparse-GEMM net-neutral (fixed costs dominate).

#define B_     4
#define N_     50000
#define M_     256
#define NCH    32                  // raw-K chunks (split-K partials)
#define NST    2                   // strips of 128 output rows
#define CHUNK  ((N_ + NCH - 1) / NCH)   // 1563
#define BLOCK  1024                // 16 waves/CU (1 block/CU, LDS-limited)
#define NWAVE  (BLOCK / 64)
#define GROWS  128
#define GCELLS (GROWS * M_)        // 32768 live u32 cells = 16384 u64 pairs
#define GP64   16384               // live u64 pairs
#define G64SZ  16576               // + dump scratch (max 16384+63+127)
#define CS2    0.72134752f         // 0.5*log2(e)
#define L127   6.9886847f          // log2(127)

#if __has_builtin(__builtin_amdgcn_exp2f)
  #define EXP2(t) __builtin_amdgcn_exp2f(t)
#else
  #define EXP2(t) exp2f(t)
#endif

__device__ __forceinline__ unsigned short bf16ru(float f) {  // round-half-up
    return (unsigned short)((__builtin_bit_cast(unsigned, f) + 0x8000u) >> 16);
}
__device__ __forceinline__ float bf2f(unsigned short u) {
    return __builtin_bit_cast(float, ((unsigned)u) << 16);
}

__global__ __launch_bounds__(BLOCK) void kde_accum(
    const float* __restrict__ xs, const float* __restrict__ ys,
    const float* __restrict__ bins, unsigned short* __restrict__ partial,
    float* __restrict__ ws2, int wide)
{
    __shared__ __align__(16) unsigned long long G64[G64SZ];  // 132,608 B
    __shared__ float sred[NWAVE];

    const int tid   = threadIdx.x;
    const int strip = blockIdx.x;          // 0..NST-1: rows [strip*128, +128)
    const int chunk = blockIdx.y;          // 0..NCH-1: raw K segment
    const int b     = blockIdx.z;
    const int lane  = tid & 63;
    const int w     = tid >> 6;

    const float bin0  = bins[0];
    const float invbw = 1.0f / (bins[1] - bin0);
    const int   rlo   = strip * GROWS;

    // ---- zero the grid (incl. dump scratch) ----
    {
        uint4* gz = (uint4*)G64;
        const uint4 z4 = {0u, 0u, 0u, 0u};
        for (int t = tid; t < G64SZ / 2; t += BLOCK) gz[t] = z4;
    }
    __syncthreads();

    const int start = chunk * CHUNK;
    const int end   = (start + CHUNK < N_) ? (start + CHUNK) : N_;
    const float* xp = xs + (size_t)b * N_;
    const float* yp = ys + (size_t)b * N_;

    const unsigned dmp = (unsigned)(GP64 + lane);   // per-lane u64 dump slot

    // software-pipelined particle loop (prefetch next round's coords)
    int k = start + tid;
    float x = 3.0e30f, y = 3.0e30f;
    if (k < end) { x = xp[k]; y = yp[k]; }
    for (; k < end; k += BLOCK) {
        float xn = 3.0e30f, yn = 3.0e30f;
        if (k + BLOCK < end) { xn = xp[k + BLOCK]; yn = yp[k + BLOCK]; }

        const float ux  = (x - bin0) * invbw;
        const float uy  = (y - bin0) * invbw;
        const float stx = rintf(ux) - 3.0f;      // window rows rx..rx+6
        const float sty = rintf(uy) - 3.0f;
        const int rx = (int)stx;
        const int ry = (int)sty;

        // active iff x-window intersects this strip AND y-window hits grid
        if (rx + 6 >= rlo && rx < rlo + GROWS && ry + 6 >= 0 && ry < M_) {
            const float dx0 = ux - stx;          // in [2.5, 3.5]
            const float dy0 = uy - sty;
            unsigned qx[7], qy[7];
            #pragma unroll
            for (int j = 0; j < 7; ++j) {
                const float dx = dx0 - (float)j;
                const float dy = dy0 - (float)j;
                qx[j] = (unsigned)(int)(EXP2(fmaf(-CS2 * dx, dx, L127)) + 0.5f);
                qy[j] = (unsigned)(int)(EXP2(fmaf(-CS2 * dy, dy, L127)) + 0.5f);
            }
            // ---- pack y window into 4 even-aligned column-pair u64s ----
            const int s  = ry & 1;               // parity (per-lane)
            const int pb0 = (ry - s) >> 1;       // first pair index (may be <0)
            const unsigned lo0 = s ? 0u    : qy[0], hi0 = s ? qy[0] : qy[1];
            const unsigned lo1 = s ? qy[1] : qy[2], hi1 = s ? qy[2] : qy[3];
            const unsigned lo2 = s ? qy[3] : qy[4], hi2 = s ? qy[4] : qy[5];
            const unsigned lo3 = s ? qy[5] : qy[6], hi3 = s ? qy[6] : 0u;
            unsigned long long ypk[4];
            ypk[0] = (unsigned long long)lo0 | ((unsigned long long)hi0 << 32);
            ypk[1] = (unsigned long long)lo1 | ((unsigned long long)hi1 << 32);
            ypk[2] = (unsigned long long)lo2 | ((unsigned long long)hi2 << 32);
            ypk[3] = (unsigned long long)lo3 | ((unsigned long long)hi3 << 32);
            unsigned pofs[4];
            #pragma unroll
            for (int t = 0; t < 4; ++t) {
                const int p = pb0 + t;           // pair col index
                pofs[t] = ((unsigned)p < 128u) ? (unsigned)p : 0x80000000u;
            }
            #pragma unroll
            for (int i = 0; i < 7; ++i) {
                const int rr = rx + i - rlo;
                const unsigned rbase =
                    ((unsigned)rr < (unsigned)GROWS) ? (unsigned)(rr << 7) : dmp;
                const unsigned long long wxi = (unsigned long long)qx[i];
                #pragma unroll
                for (int t = 0; t < 4; ++t) {
                    unsigned a = rbase + pofs[t];
                    a = ((int)a < 0) ? dmp : a;  // invalid pair -> dump slot
                    atomicAdd(&G64[a], wxi * ypk[t]);    // ds_add_u64
                }
            }
        }
        x = xn; y = yn;
    }
    __syncthreads();                         // all waves' atomics complete

    // ---- epilogue: i32 grid -> bf16 split-K partial + strip sum ----
    // u32 view of G64: index r*256+c == exact R18 layout (little-endian).
    const unsigned int* Gv = (const unsigned int*)G64;
    unsigned short* pb = partial + (((size_t)chunk * B_ + b) << 16);
    float tsum = 0.f;
    #pragma unroll
    for (int rep = 0; rep < GCELLS / (BLOCK * 4); ++rep) {   // 8 reps
        const int cell = rep * (BLOCK * 4) + tid * 4;
        const uint4 gv = *(const uint4*)&Gv[cell];           // ds_read_b128
        const float f0 = (float)gv.x, f1 = (float)gv.y;
        const float f2 = (float)gv.z, f3 = (float)gv.w;
        tsum += (f0 + f1) + (f2 + f3);
        ushort4 o;
        o.x = bf16ru(f0); o.y = bf16ru(f1); o.z = bf16ru(f2); o.w = bf16ru(f3);
        const int r = cell >> 8;             // strip-local row
        const int c = cell & (M_ - 1);       // col (multiple of 4)
        *(ushort4*)&pb[(size_t)(rlo + r) * M_ + c] = o;
    }

    // ---- block sum -> ws2 ----
    #pragma unroll
    for (int off = 32; off; off >>= 1) tsum += __shfl_xor(tsum, off);
    if (lane == 0) sred[w] = tsum;
    __syncthreads();
    if (tid == 0) {
        float bsum = 0.f;
        #pragma unroll
        for (int i = 0; i < NWAVE; ++i) bsum += sred[i];
        if (wide) {
            const int bid = (b * NCH + chunk) * NST + strip;   // < 256
            ws2[bid] = bsum;
        } else {
            atomicAdd(&ws2[b], bsum);
        }
    }
}

__global__ __launch_bounds__(256) void kde_tail(
    const unsigned short* __restrict__ partial, const float* __restrict__ ws2,
    float* __restrict__ out, int wide)
{
    __shared__ float sred[4];
    __shared__ float snorm;
    const int tid = threadIdx.x;
    const int cellIdx = blockIdx.x * 256 + tid;     // float4 index, 16384/batch
    const int bb = cellIdx >> 14;                   // uniform per block
    const int cb = cellIdx & 16383;

    float nrm;
    if (wide) {
        float t = (tid < NCH * NST) ? ws2[bb * (NCH * NST) + tid] : 0.f;
        #pragma unroll
        for (int off = 32; off; off >>= 1) t += __shfl_xor(t, off);
        if ((tid & 63) == 0) sred[tid >> 6] = t;
        __syncthreads();
        if (tid == 0) snorm = sred[0] + sred[1] + sred[2] + sred[3];
        __syncthreads();
        nrm = snorm;
    } else {
        nrm = ws2[bb];
    }

    float4 a = {0.f, 0.f, 0.f, 0.f};
    #pragma unroll 4
    for (int c = 0; c < NCH; ++c) {
        const ushort4 v = *(const ushort4*)(partial +
            (((size_t)c * B_ + bb) << 16) + (size_t)cb * 4);
        a.x += bf2f(v.x); a.y += bf2f(v.y); a.z += bf2f(v.z); a.w += bf2f(v.w);
    }
    // i8 scale (127^2) cancels: both partials and nrm carry it.
    const float sc = 1.0f / (nrm + 1e-10f);
    a.x *= sc; a.y *= sc; a.z *= sc; a.w *= sc;
    ((float4*)out)[cellIdx] = a;
}

extern "C" void kernel_launch(void* const* d_in, const int* in_sizes, int n_in,
                              void* d_out, int out_size, void* d_ws, size_t ws_size,
                              hipStream_t stream)
{
    const float* xs   = (const float*)d_in[0];
    const float* ys   = (const float*)d_in[1];
    const float* bins = (const float*)d_in[2];
    float* out = (float*)d_out;

    unsigned short* partial = (unsigned short*)d_ws;        // 16.8 MB bf16
    const size_t PSZ = (size_t)NCH * B_ * M_ * M_ * sizeof(unsigned short);
    float* ws2 = (float*)((char*)d_ws + PSZ);               // 256 f32 (wide)

    const int wide = (ws_size >= PSZ + 4096) ? 1 : 0;
    if (!wide) hipMemsetAsync(ws2, 0, 4 * sizeof(float), stream);

    kde_accum<<<dim3(NST, NCH, B_), dim3(BLOCK), 0, stream>>>(
        xs, ys, bins, partial, ws2, wide);
    kde_tail<<<dim3(B_ * M_ * M_ / (4 * 256)), dim3(256), 0, stream>>>(
        partial, ws2, out, wide);
}